// Round 13
// baseline (312.208 us; speedup 1.0000x reference)
//
#include <hip/hip_runtime.h>
#include <math.h>

#define NODES_C 256
#define NEG_SLOPE 0.2f
#define CAP 128               // padded-CSR capacity; max degree here ~65 (17-sigma margin)
#define NSLICE 8              // one destination-slice per XCD (blockIdx % 8 heuristic)
#define AROWS 64              // rows per a_s/a_d block in k_init

typedef __attribute__((ext_vector_type(8))) short short8;
typedef __attribute__((ext_vector_type(4))) float f32x4;
typedef __attribute__((ext_vector_type(2))) float f32x2;
typedef __attribute__((ext_vector_type(4))) int i32x4;
typedef __attribute__((ext_vector_type(2))) unsigned u32x2;

__device__ inline unsigned short f2bf(float f) {   // RNE float->bf16
    unsigned u = __float_as_uint(f);
    u = (u + 0x7fff + ((u >> 16) & 1)) >> 16;
    return (unsigned short)u;
}
__device__ inline unsigned cvtpk_bf16(float a, float b) {
    unsigned r;
    asm("v_cvt_pk_bf16_f32 %0, %1, %2" : "=v"(r) : "v"(a), "v"(b));
    return r;
}
__device__ inline void gload_lds16(const void* g, void* l) {
    __builtin_amdgcn_global_load_lds(
        (const __attribute__((address_space(1))) unsigned int*)g,
        (__attribute__((address_space(3))) unsigned int*)l, 16, 0, 0);
}
// acc += w * unpack_bf16_pair(u)
__device__ inline void fma2(f32x2& a, unsigned u, float w) {
    f32x2 h;
    h.x = __uint_as_float(u << 16);
    h.y = __uint_as_float(u & 0xffff0000u);
    a += h * w;
}
// T2 swizzle: XOR 16B-granule index with row&7 (involution, both sides)
__device__ inline int swz(int row, int e) { return e ^ ((row & 7) << 3); }

// ============ k_init (fat): a_s/a_d matvec || cvt_w || zero cnt ===========
// a_s = x @ (W@att_src): associativity removes the h-dependency so permute
// can legally overlap the GEMM in k_fat.
__global__ __launch_bounds__(256) void k_init(
    const float* __restrict__ x, const float* __restrict__ W,
    const float* __restrict__ att_src, const float* __restrict__ att_dst,
    unsigned short* __restrict__ wt, float* __restrict__ a_s,
    float* __restrict__ a_d, int* __restrict__ cnt,
    int n, int nbA, int nbCvtw) {
    const int tid = threadIdx.x;
    int bid = blockIdx.x;
    if (bid < nbA) {                           // ---- a_s / a_d over 64 rows ----
        __shared__ float vs[NODES_C], vd[NODES_C];
        {   // thread j: vs[j] = W[j,:] . att_src  (W 256KB, L2-resident)
            const float4* wr = (const float4*)(W + (size_t)tid * NODES_C);
            const float4* as4 = (const float4*)att_src;
            const float4* ad4 = (const float4*)att_dst;
            float s = 0.f, d = 0.f;
            for (int c = 0; c < NODES_C / 4; ++c) {
                const float4 wv = wr[c], av = as4[c], bv = ad4[c];
                s += wv.x * av.x + wv.y * av.y + wv.z * av.z + wv.w * av.w;
                d += wv.x * bv.x + wv.y * bv.y + wv.z * bv.z + wv.w * bv.w;
            }
            vs[tid] = s; vd[tid] = d;
        }
        __syncthreads();
        const int lane = tid & 63, wid = tid >> 6;
        const float4 vsl = ((const float4*)vs)[lane];
        const float4 vdl = ((const float4*)vd)[lane];
        const int rend = min(bid * AROWS + AROWS, n);
        for (int r = bid * AROWS + wid; r < rend; r += 4) {
            const f32x4 xv = __builtin_nontemporal_load(
                &((const f32x4*)(x + (size_t)r * NODES_C))[lane]);
            float s = xv.x * vsl.x + xv.y * vsl.y + xv.z * vsl.z + xv.w * vsl.w;
            float d = xv.x * vdl.x + xv.y * vdl.y + xv.z * vdl.z + xv.w * vdl.w;
#pragma unroll
            for (int off = 32; off; off >>= 1) {
                s += __shfl_xor(s, off);
                d += __shfl_xor(d, off);
            }
            if (lane == 0) { a_s[r] = s; a_d[r] = d; }
        }
        return;
    }
    bid -= nbA;
    if (bid < nbCvtw) {                        // ---- W -> wt (bf16, transposed) ----
        const int base = bid * 1024 + tid;
#pragma unroll
        for (int k = 0; k < 4; ++k) {
            const int i = base + k * 256;
            wt[i] = f2bf(W[(i & 255) * NODES_C + (i >> 8)]);
        }
        return;
    }
    bid -= nbCvtw;                             // ---- zero cnt ----
    const int base = bid * 1024 + tid;
#pragma unroll
    for (int k = 0; k < 4; ++k) {
        const int i = base + k * 256;
        if (i < n) cnt[i] = 0;
    }
}

// ============ k_fat: GEMM (NT streams) || XCD-sliced permute ==============
// GEMM role uses nontemporal x-loads and hb-stores so its streams do not
// evict permute's L2-resident bins (R9's failure mode).
__global__ __launch_bounds__(256) void k_fat(
    const float* __restrict__ x, const unsigned short* __restrict__ wt,
    unsigned short* __restrict__ hb,
    const int* __restrict__ src, const int* __restrict__ dst,
    const float* __restrict__ a_s, const float* __restrict__ a_d,
    int* __restrict__ cnt, unsigned* __restrict__ sedge,
    int n, int nbG, int E4, int bps, int nsNode) {
    __shared__ unsigned short Ab[128 * 64];
    __shared__ unsigned short Bb[128 * 64];
    const int tid = threadIdx.x;

    if (blockIdx.x >= nbG) {
        // ---------------- permute role (XCD-sliced padded-CSR scatter) ----
        // slice from ABSOLUTE blockIdx&7 (round-robin XCD heuristic).
        const int slice = blockIdx.x & (NSLICE - 1);
        const int j = (blockIdx.x - nbG) >> 3;     // 0..bps-1 per slice
        const int lo = slice * nsNode;
        const int hi = min(lo + nsNode, n);
        const int stride = bps * 256;
        const i32x4* d4 = (const i32x4*)dst;
        const i32x4* s4 = (const i32x4*)src;
        for (int g = j * 256 + tid; g < E4; g += 2 * stride) {
            const int g2 = g + stride;
            const bool has2 = g2 < E4;
            const i32x4 dvA = __builtin_nontemporal_load(&d4[g]);
            i32x4 dvB = {lo - 1, lo - 1, lo - 1, lo - 1};
            if (has2) dvB = __builtin_nontemporal_load(&d4[g2]);
            const bool a0 = (dvA.x >= lo) & (dvA.x < hi);
            const bool a1 = (dvA.y >= lo) & (dvA.y < hi);
            const bool a2 = (dvA.z >= lo) & (dvA.z < hi);
            const bool a3 = (dvA.w >= lo) & (dvA.w < hi);
            const bool b0 = (dvB.x >= lo) & (dvB.x < hi);
            const bool b1 = (dvB.y >= lo) & (dvB.y < hi);
            const bool b2 = (dvB.z >= lo) & (dvB.z < hi);
            const bool b3 = (dvB.w >= lo) & (dvB.w < hi);
            if (a0 | a1 | a2 | a3) {
                const i32x4 sv = __builtin_nontemporal_load(&s4[g]);
#pragma unroll
                for (int k = 0; k < 4; ++k) {
                    const bool mk = k == 0 ? a0 : k == 1 ? a1 : k == 2 ? a2 : a3;
                    if (!mk) continue;
                    const int d = k == 0 ? dvA.x : k == 1 ? dvA.y : k == 2 ? dvA.z : dvA.w;
                    const int s = k == 0 ? sv.x : k == 1 ? sv.y : k == 2 ? sv.z : sv.w;
                    float e = a_s[s] + a_d[d];
                    e = e > 0.f ? e : NEG_SLOPE * e;
                    const float w = __expf(e);
                    const int pos = atomicAdd(&cnt[d], 1);
                    if (pos < CAP) sedge[(d << 7) + pos] = ((unsigned)f2bf(w) << 16) | (unsigned)s;
                }
            }
            if (b0 | b1 | b2 | b3) {
                const i32x4 sv = __builtin_nontemporal_load(&s4[g2]);
#pragma unroll
                for (int k = 0; k < 4; ++k) {
                    const bool mk = k == 0 ? b0 : k == 1 ? b1 : k == 2 ? b2 : b3;
                    if (!mk) continue;
                    const int d = k == 0 ? dvB.x : k == 1 ? dvB.y : k == 2 ? dvB.z : dvB.w;
                    const int s = k == 0 ? sv.x : k == 1 ? sv.y : k == 2 ? sv.z : sv.w;
                    float e = a_s[s] + a_d[d];
                    e = e > 0.f ? e : NEG_SLOPE * e;
                    const float w = __expf(e);
                    const int pos = atomicAdd(&cnt[d], 1);
                    if (pos < CAP) sedge[(d << 7) + pos] = ((unsigned)f2bf(w) << 16) | (unsigned)s;
                }
            }
        }
        return;
    }

    // ---------------- GEMM role: 128x128, BK=64, swizzled LDS -------------
    const int lane = tid & 63;
    const int wid = tid >> 6;
    // bijective chunked XCD swizzle over the nbG GEMM blocks (m204)
    const int q8 = nbG >> 3, r8 = nbG & 7;
    const int xcd = blockIdx.x & 7, jj = blockIdx.x >> 3;
    const int t = (xcd < r8 ? xcd * (q8 + 1) : r8 * (q8 + 1) + (xcd - r8) * q8) + jj;

    const int wr = wid >> 1, wc = wid & 1;
    const int brow = (t >> 1) * 128;
    const int bcol = (t & 1) * 128;
    const int rsel = lane & 15, ksel = (lane >> 4) * 8;

    f32x4 acc[4][4] = {};   // acc[m][q] = h^T fragment (swapped operands)

    const int bc0 = wid * 4;
    const int srB = lane >> 3;                // row within chunk (0..7)
    const int gcB = swz(srB, (lane & 7) * 8); // pre-swizzled global k-offset
    const int arow = tid >> 1;
    const int kh = (tid & 1) * 32;
    const f32x4* xsrc = (const f32x4*)(x + (size_t)min(brow + arow, n - 1) * NODES_C);

    for (int kk = 0; kk < 256; kk += 64) {
        const int kb = (kk + kh) >> 2;
        f32x4 v[8];
#pragma unroll
        for (int i = 0; i < 8; ++i) v[i] = __builtin_nontemporal_load(&xsrc[kb + i]);
#pragma unroll
        for (int c = 0; c < 4; ++c) {
            const int ch = bc0 + c;
            gload_lds16(wt + (size_t)(bcol + ch * 8 + srB) * NODES_C + kk + gcB,
                        Bb + ch * 512);
        }
#pragma unroll
        for (int i = 0; i < 4; ++i)
            *(uint4*)&Ab[arow * 64 + swz(arow, kh + 8 * i)] =
                make_uint4(cvtpk_bf16(v[2 * i].x, v[2 * i].y),
                           cvtpk_bf16(v[2 * i].z, v[2 * i].w),
                           cvtpk_bf16(v[2 * i + 1].x, v[2 * i + 1].y),
                           cvtpk_bf16(v[2 * i + 1].z, v[2 * i + 1].w));
        __syncthreads();
#pragma unroll
        for (int ks = 0; ks < 64; ks += 32) {
            short8 afrag[4], bfrag[4];
#pragma unroll
            for (int m = 0; m < 4; ++m) {
                const int r = wr * 64 + m * 16 + rsel;
                afrag[m] = *(const short8*)&Ab[r * 64 + swz(r, ksel + ks)];
            }
#pragma unroll
            for (int q = 0; q < 4; ++q) {
                const int r = wc * 64 + q * 16 + rsel;
                bfrag[q] = *(const short8*)&Bb[r * 64 + swz(r, ksel + ks)];
            }
#pragma unroll
            for (int m = 0; m < 4; ++m)
#pragma unroll
                for (int q = 0; q < 4; ++q)   // SWAPPED operands -> h^T frag
                    acc[m][q] = __builtin_amdgcn_mfma_f32_16x16x32_bf16(bfrag[q], afrag[m], acc[m][q], 0, 0, 0);
        }
        __syncthreads();
    }

    // epilogue: lane owns x-row (lane&15); NT-store 4 consecutive cols/frag
    const int xr = lane & 15;
    const int cg = (lane >> 4) * 4;   // 0,4,8,12
#pragma unroll
    for (int m = 0; m < 4; ++m) {
        const int r = brow + wr * 64 + m * 16 + xr;
        if (r < n) {
#pragma unroll
            for (int q = 0; q < 4; ++q) {
                const f32x4 v = acc[m][q];
                u32x2 hv;
                hv.x = cvtpk_bf16(v[0], v[1]);
                hv.y = cvtpk_bf16(v[2], v[3]);
                __builtin_nontemporal_store(
                    hv, (u32x2*)&hb[(size_t)r * NODES_C + bcol + wc * 64 + q * 16 + cg]);
            }
        }
    }
}

// ============ gather: pair-rows, fully static register arrays =============
__global__ __launch_bounds__(256) void k_gather(const int* __restrict__ cnt,
                                                const unsigned* __restrict__ sedge,
                                                const unsigned short* __restrict__ hb,
                                                const float* __restrict__ a_s,
                                                const float* __restrict__ a_d,
                                                const float* __restrict__ bias,
                                                float* __restrict__ out, int n) {
    const int node = (int)((blockIdx.x * (size_t)blockDim.x + threadIdx.x) >> 6);
    const int lane = threadIdx.x & 63;
    if (node >= n) return;
    const int c = min(__builtin_amdgcn_readfirstlane(cnt[node]), CAP);
    const int base = node << 7;
    const int hf = lane >> 5, q = lane & 31;
    const uint4* hrow = (const uint4*)hb;     // row = 32 uint4 (512 B)

    // self-loop meta (packed same as edges)
    float eself = a_s[node] + a_d[node];
    eself = eself > 0.f ? eself : NEG_SLOPE * eself;
    const unsigned selfmeta = ((unsigned)f2bf(__expf(eself)) << 16) | (unsigned)node;
    const int items = c + 1;

    f32x2 acc0 = {0.f, 0.f}, acc1 = {0.f, 0.f}, acc2 = {0.f, 0.f}, acc3 = {0.f, 0.f};
    float dsum = 0.f;   // per-half partial

    int it = 0;
    for (; it + 16 <= c; it += 16) {          // 8 pair-rows in flight, all regs named
        const int bi = __builtin_amdgcn_readfirstlane(base + it);
        const uint4 pA = *(const uint4*)&sedge[bi];
        const uint4 pB = *(const uint4*)&sedge[bi + 4];
        const uint4 pC = *(const uint4*)&sedge[bi + 8];
        const uint4 pD = *(const uint4*)&sedge[bi + 12];
        const unsigned m0 = hf ? pA.y : pA.x;
        const unsigned m1 = hf ? pA.w : pA.z;
        const unsigned m2 = hf ? pB.y : pB.x;
        const unsigned m3 = hf ? pB.w : pB.z;
        const unsigned m4 = hf ? pC.y : pC.x;
        const unsigned m5 = hf ? pC.w : pC.z;
        const unsigned m6 = hf ? pD.y : pD.x;
        const unsigned m7 = hf ? pD.w : pD.z;
        const uint4 r0 = hrow[(size_t)(m0 & 0xffffu) * 32 + q];
        const uint4 r1 = hrow[(size_t)(m1 & 0xffffu) * 32 + q];
        const uint4 r2 = hrow[(size_t)(m2 & 0xffffu) * 32 + q];
        const uint4 r3 = hrow[(size_t)(m3 & 0xffffu) * 32 + q];
        const uint4 r4 = hrow[(size_t)(m4 & 0xffffu) * 32 + q];
        const uint4 r5 = hrow[(size_t)(m5 & 0xffffu) * 32 + q];
        const uint4 r6 = hrow[(size_t)(m6 & 0xffffu) * 32 + q];
        const uint4 r7 = hrow[(size_t)(m7 & 0xffffu) * 32 + q];
        float w;
        w = __uint_as_float(m0 & 0xffff0000u); dsum += w;
        fma2(acc0, r0.x, w); fma2(acc1, r0.y, w); fma2(acc2, r0.z, w); fma2(acc3, r0.w, w);
        w = __uint_as_float(m1 & 0xffff0000u); dsum += w;
        fma2(acc0, r1.x, w); fma2(acc1, r1.y, w); fma2(acc2, r1.z, w); fma2(acc3, r1.w, w);
        w = __uint_as_float(m2 & 0xffff0000u); dsum += w;
        fma2(acc0, r2.x, w); fma2(acc1, r2.y, w); fma2(acc2, r2.z, w); fma2(acc3, r2.w, w);
        w = __uint_as_float(m3 & 0xffff0000u); dsum += w;
        fma2(acc0, r3.x, w); fma2(acc1, r3.y, w); fma2(acc2, r3.z, w); fma2(acc3, r3.w, w);
        w = __uint_as_float(m4 & 0xffff0000u); dsum += w;
        fma2(acc0, r4.x, w); fma2(acc1, r4.y, w); fma2(acc2, r4.z, w); fma2(acc3, r4.w, w);
        w = __uint_as_float(m5 & 0xffff0000u); dsum += w;
        fma2(acc0, r5.x, w); fma2(acc1, r5.y, w); fma2(acc2, r5.z, w); fma2(acc3, r5.w, w);
        w = __uint_as_float(m6 & 0xffff0000u); dsum += w;
        fma2(acc0, r6.x, w); fma2(acc1, r6.y, w); fma2(acc2, r6.z, w); fma2(acc3, r6.w, w);
        w = __uint_as_float(m7 & 0xffff0000u); dsum += w;
        fma2(acc0, r7.x, w); fma2(acc1, r7.y, w); fma2(acc2, r7.z, w); fma2(acc3, r7.w, w);
    }
    for (; it < items; it += 2) {             // tail (includes self at index c)
        const int bi = __builtin_amdgcn_readfirstlane(base + it);
        const unsigned t0 = (it     < c) ? sedge[bi]     : ((it     == c) ? selfmeta : 0u);
        const unsigned t1 = (it + 1 < c) ? sedge[bi + 1] : ((it + 1 == c) ? selfmeta : 0u);
        const unsigned m = hf ? t1 : t0;
        const uint4 r = hrow[(size_t)(m & 0xffffu) * 32 + q];
        const float w = __uint_as_float(m & 0xffff0000u);
        dsum += w;
        fma2(acc0, r.x, w); fma2(acc1, r.y, w);
        fma2(acc2, r.z, w); fma2(acc3, r.w, w);
    }

    // combine halves (edge subsets were split across lane halves)
    dsum += __shfl_xor(dsum, 32);
    acc0.x += __shfl_xor(acc0.x, 32); acc0.y += __shfl_xor(acc0.y, 32);
    acc1.x += __shfl_xor(acc1.x, 32); acc1.y += __shfl_xor(acc1.y, 32);
    acc2.x += __shfl_xor(acc2.x, 32); acc2.y += __shfl_xor(acc2.y, 32);
    acc3.x += __shfl_xor(acc3.x, 32); acc3.y += __shfl_xor(acc3.y, 32);

    const float inv = 1.f / dsum;
    const f32x2 A = hf ? acc2 : acc0;         // this lane's 4 output channels
    const f32x2 B = hf ? acc3 : acc1;
    const int ch = q * 8 + hf * 4;
    const float4 b4 = *(const float4*)&bias[ch];
    float4 o;
    o.x = fmaf(A.x, inv, b4.x);
    o.y = fmaf(A.y, inv, b4.y);
    o.z = fmaf(B.x, inv, b4.z);
    o.w = fmaf(B.y, inv, b4.w);
    *(float4*)&out[(size_t)node * NODES_C + ch] = o;
}

extern "C" void kernel_launch(void* const* d_in, const int* in_sizes, int n_in,
                              void* d_out, int out_size, void* d_ws, size_t ws_size,
                              hipStream_t stream) {
    const float* x       = (const float*)d_in[0];
    const int*   edge    = (const int*)d_in[1];
    const float* W       = (const float*)d_in[2];
    const float* att_src = (const float*)d_in[3];
    const float* att_dst = (const float*)d_in[4];
    const float* bias    = (const float*)d_in[5];
    float* out = (float*)d_out;

    const int n = in_sizes[0] / NODES_C;   // 50000
    const int E = in_sizes[1] / 2;         // 1600000
    const int Mpad = (n + 127) & ~127;     // 50048
    const int* src = edge;
    const int* dst = edge + E;

    // workspace carve (256B-aligned blocks)
    char* p = (char*)d_ws;
    auto carve = [&p](size_t bytes) { char* r = p; p += (bytes + 255) & ~(size_t)255; return r; };
    unsigned short* wt = (unsigned short*)carve((size_t)NODES_C * NODES_C * 2);
    unsigned short* hb = (unsigned short*)carve((size_t)n * NODES_C * 2);     // 25.6 MB
    float* a_s = (float*)carve((size_t)n * 4);
    float* a_d = (float*)carve((size_t)n * 4);
    int*   cnt = (int*)carve((size_t)n * 4);
    unsigned* sedge = (unsigned*)carve((size_t)n * CAP * 4);                  // 25.6 MB

    const int nbA    = (n + AROWS - 1) / AROWS;          // 782
    const int nbCvtw = (NODES_C * NODES_C) / 1024;       // 64
    const int nbZ    = (n + 1023) / 1024;                // 49

    k_init<<<nbA + nbCvtw + nbZ, 256, 0, stream>>>(
        x, W, att_src, att_dst, wt, a_s, a_d, cnt, n, nbA, nbCvtw);

    const int nbG = (Mpad / 128) * 2;                    // 782 GEMM blocks
    const int E4 = E / 4;                                // 400000 (E % 4 == 0)
    const int bps = 192;                                 // permute blocks per slice
    const int nsNode = (n + NSLICE - 1) / NSLICE;        // 6250
    k_fat<<<nbG + bps * NSLICE, 256, 0, stream>>>(
        x, wt, hb, src, dst, a_s, a_d, cnt, sedge, n, nbG, E4, bps, nsNode);

    k_gather<<<(n + 3) / 4, 256, 0, stream>>>(cnt, sedge, hb, a_s, a_d, bias, out, n);
}

// Round 14
// 226.579 us; speedup vs baseline: 1.3779x; 1.3779x over previous
//
#include <hip/hip_runtime.h>
#include <math.h>

#define NODES_C 256
#define NEG_SLOPE 0.2f
#define CAP 128               // padded-CSR capacity; max degree here ~65 (17-sigma margin)
#define NSLICE 8              // one destination-slice per XCD (blockIdx % 8 heuristic)

typedef __attribute__((ext_vector_type(8))) short short8;
typedef __attribute__((ext_vector_type(4))) float f32x4;
typedef __attribute__((ext_vector_type(2))) float f32x2;
typedef __attribute__((ext_vector_type(4))) int i32x4;

__device__ inline unsigned short f2bf(float f) {   // RNE float->bf16
    unsigned u = __float_as_uint(f);
    u = (u + 0x7fff + ((u >> 16) & 1)) >> 16;
    return (unsigned short)u;
}
__device__ inline unsigned cvtpk_bf16(float a, float b) {
    unsigned r;
    asm("v_cvt_pk_bf16_f32 %0, %1, %2" : "=v"(r) : "v"(a), "v"(b));
    return r;
}
__device__ inline void gload_lds16(const void* g, void* l) {
    __builtin_amdgcn_global_load_lds(
        (const __attribute__((address_space(1))) unsigned int*)g,
        (__attribute__((address_space(3))) unsigned int*)l, 16, 0, 0);
}
// acc += w * unpack_bf16_pair(u)
__device__ inline void fma2(f32x2& a, unsigned u, float w) {
    f32x2 h;
    h.x = __uint_as_float(u << 16);
    h.y = __uint_as_float(u & 0xffff0000u);
    a += h * w;
}

// ============ init (fat): zero a_s|a_d|cnt || cvt_w =======================
__global__ __launch_bounds__(256) void k_init(const float* __restrict__ W,
                                              unsigned short* __restrict__ wt,
                                              uint4* __restrict__ zbase,
                                              int nZero4, int nbZero) {
    const int tid = threadIdx.x;
    int bid = blockIdx.x;
    if (bid < nbZero) {                        // ---- zero 3n floats ----
        const int base = bid * 1024 + tid;
#pragma unroll
        for (int k = 0; k < 4; ++k) {
            const int i = base + k * 256;
            if (i < nZero4) zbase[i] = make_uint4(0, 0, 0, 0);
        }
        return;
    }
    bid -= nbZero;                             // ---- W -> wt (bf16, transposed) ----
    const int base = bid * 1024 + tid;
#pragma unroll
    for (int k = 0; k < 4; ++k) {
        const int i = base + k * 256;
        wt[i] = f2bf(W[(i & 255) * NODES_C + (i >> 8)]);
    }
}

// ============ Stage B: gemm (128x128 tile) + fused attn epilogue ==========
// A-tiles reg-staged from fp32 x (cvt_pk in-flight); B via global_load_lds.
__global__ __launch_bounds__(256) void k_stageB(
    const float* __restrict__ x, const unsigned short* __restrict__ wt,
    const float* __restrict__ att_src, const float* __restrict__ att_dst,
    unsigned short* __restrict__ hb, float* __restrict__ a_s, float* __restrict__ a_d,
    int n) {
    __shared__ unsigned short Ab[128 * 32];
    __shared__ unsigned short Bb[128 * 32];
    __shared__ float pfs[2][128], pfd[2][128];
    const int tid = threadIdx.x;
    const int lane = tid & 63;
    const int wid = tid >> 6;

    const int gbid = blockIdx.x;
    const int wr = wid >> 1, wc = wid & 1;
    const int brow = (gbid >> 1) * 128;
    const int bcol = (gbid & 1) * 128;
    const int rsel = lane & 15, ksel = (lane >> 4) * 8;

    f32x4 acc[4][4] = {};   // acc[m][q] = h^T fragment (swapped operands)
    const int c0 = wid, c1 = wid + 4;
    const int srow0 = c0 * 16 + (lane >> 2), srow1 = c1 * 16 + (lane >> 2);
    const int sk = (lane & 3) * 8;
    const int arow = tid >> 1;
    const int kh = (tid & 1) * 16;
    const float4* xsrc = (const float4*)(x + (size_t)min(brow + arow, n - 1) * NODES_C);
    uint4* adst = (uint4*)&Ab[arow * 32 + kh];

    for (int kk = 0; kk < 256; kk += 32) {
        const int kb = (kk + kh) >> 2;
        const float4 v0 = xsrc[kb + 0];
        const float4 v1 = xsrc[kb + 1];
        const float4 v2 = xsrc[kb + 2];
        const float4 v3 = xsrc[kb + 3];
        gload_lds16(wt + (size_t)(bcol + srow0) * NODES_C + kk + sk, Bb + c0 * 512);
        gload_lds16(wt + (size_t)(bcol + srow1) * NODES_C + kk + sk, Bb + c1 * 512);
        adst[0] = make_uint4(cvtpk_bf16(v0.x, v0.y), cvtpk_bf16(v0.z, v0.w),
                             cvtpk_bf16(v1.x, v1.y), cvtpk_bf16(v1.z, v1.w));
        adst[1] = make_uint4(cvtpk_bf16(v2.x, v2.y), cvtpk_bf16(v2.z, v2.w),
                             cvtpk_bf16(v3.x, v3.y), cvtpk_bf16(v3.z, v3.w));
        __syncthreads();
        short8 afrag[4], bfrag[4];
#pragma unroll
        for (int m = 0; m < 4; ++m)
            afrag[m] = *(const short8*)&Ab[(wr * 64 + m * 16 + rsel) * 32 + ksel];
#pragma unroll
        for (int q = 0; q < 4; ++q)
            bfrag[q] = *(const short8*)&Bb[(wc * 64 + q * 16 + rsel) * 32 + ksel];
#pragma unroll
        for (int m = 0; m < 4; ++m)
#pragma unroll
            for (int q = 0; q < 4; ++q)   // SWAPPED operands -> h^T frag
                acc[m][q] = __builtin_amdgcn_mfma_f32_16x16x32_bf16(bfrag[q], afrag[m], acc[m][q], 0, 0, 0);
        __syncthreads();
    }

    // epilogue: lane owns x-row (lane&15), 4 consecutive out-cols per frag
    const int xr = lane & 15;
    const int cg = (lane >> 4) * 4;   // 0,4,8,12
    float4 avs4[4], avd4[4];
#pragma unroll
    for (int q = 0; q < 4; ++q) {
        avs4[q] = *(const float4*)&att_src[bcol + wc * 64 + q * 16 + cg];
        avd4[q] = *(const float4*)&att_dst[bcol + wc * 64 + q * 16 + cg];
    }
#pragma unroll
    for (int m = 0; m < 4; ++m) {
        const int rloc = wr * 64 + m * 16 + xr;
        const int r = brow + rloc;
        float s = 0.f, d = 0.f;
#pragma unroll
        for (int q = 0; q < 4; ++q) {
            const f32x4 v = acc[m][q];
            s += v[0] * avs4[q].x + v[1] * avs4[q].y + v[2] * avs4[q].z + v[3] * avs4[q].w;
            d += v[0] * avd4[q].x + v[1] * avd4[q].y + v[2] * avd4[q].z + v[3] * avd4[q].w;
            if (r < n) {
                const uint2 hv = make_uint2(cvtpk_bf16(v[0], v[1]), cvtpk_bf16(v[2], v[3]));
                *(uint2*)&hb[(size_t)r * NODES_C + bcol + wc * 64 + q * 16 + cg] = hv;
            }
        }
        s += __shfl_xor(s, 16); s += __shfl_xor(s, 32);
        d += __shfl_xor(d, 16); d += __shfl_xor(d, 32);
        if (lane < 16) { pfs[wc][rloc] = s; pfd[wc][rloc] = d; }
    }
    __syncthreads();
    if (tid < 128) {
        const int r = brow + tid;
        if (r < n) atomicAdd(&a_s[r], pfs[0][tid] + pfs[1][tid]);
    } else {
        const int t2 = tid - 128;
        const int r = brow + t2;
        if (r < n) atomicAdd(&a_d[r], pfd[0][t2] + pfd[1][t2]);
    }
}

// ============ permute: XCD-sliced padded-CSR scatter (standalone) ========
// Block handles dst-slice (blockIdx & 7) -> its bin writes + cnt atomics stay
// in one XCD's L2 (3.2 MB < 4 MB). NT-streams dst/src (8x logical amp,
// LLC-absorbed). MUST stay a standalone kernel: co-residency with streaming
// roles (R9 plain, R13 NT-protected) evicts the bins and restores 64B
// write-amplification (87-120 MB WRITE_SIZE vs ~10 MB standalone).
__global__ __launch_bounds__(256) void k_permute(const int* __restrict__ src,
                                                 const int* __restrict__ dst,
                                                 const float* __restrict__ a_s,
                                                 const float* __restrict__ a_d,
                                                 int* __restrict__ cnt,
                                                 unsigned* __restrict__ sedge,
                                                 int E4, int bps, int nsNode, int n) {
    const int slice = blockIdx.x & (NSLICE - 1);
    const int j = blockIdx.x >> 3;
    const int lo = slice * nsNode;
    const int hi = min(lo + nsNode, n);
    const int stride = bps * 256;
    const i32x4* d4 = (const i32x4*)dst;
    const i32x4* s4 = (const i32x4*)src;

    for (int g = j * 256 + threadIdx.x; g < E4; g += stride) {
        const i32x4 dv = __builtin_nontemporal_load(&d4[g]);
        const bool m0 = (dv.x >= lo) & (dv.x < hi);
        const bool m1 = (dv.y >= lo) & (dv.y < hi);
        const bool m2 = (dv.z >= lo) & (dv.z < hi);
        const bool m3 = (dv.w >= lo) & (dv.w < hi);
        if (!(m0 | m1 | m2 | m3)) continue;
        const i32x4 sv = __builtin_nontemporal_load(&s4[g]);
#pragma unroll
        for (int k = 0; k < 4; ++k) {
            const bool mk = k == 0 ? m0 : k == 1 ? m1 : k == 2 ? m2 : m3;
            if (!mk) continue;
            const int d = k == 0 ? dv.x : k == 1 ? dv.y : k == 2 ? dv.z : dv.w;
            const int s = k == 0 ? sv.x : k == 1 ? sv.y : k == 2 ? sv.z : sv.w;
            float e = a_s[s] + a_d[d];
            e = e > 0.f ? e : NEG_SLOPE * e;
            const float w = __expf(e);   // |e| small: safe; softmax shift-invariant
            const int pos = atomicAdd(&cnt[d], 1);
            if (pos < CAP) sedge[(d << 7) + pos] = ((unsigned)f2bf(w) << 16) | (unsigned)s;
        }
    }
}

// ============ gather: pair-rows, fully static register arrays =============
__global__ __launch_bounds__(256) void k_gather(const int* __restrict__ cnt,
                                                const unsigned* __restrict__ sedge,
                                                const unsigned short* __restrict__ hb,
                                                const float* __restrict__ a_s,
                                                const float* __restrict__ a_d,
                                                const float* __restrict__ bias,
                                                float* __restrict__ out, int n) {
    const int node = (int)((blockIdx.x * (size_t)blockDim.x + threadIdx.x) >> 6);
    const int lane = threadIdx.x & 63;
    if (node >= n) return;
    const int c = min(__builtin_amdgcn_readfirstlane(cnt[node]), CAP);
    const int base = node << 7;
    const int hf = lane >> 5, q = lane & 31;
    const uint4* hrow = (const uint4*)hb;     // row = 32 uint4 (512 B)

    // self-loop meta (packed same as edges)
    float eself = a_s[node] + a_d[node];
    eself = eself > 0.f ? eself : NEG_SLOPE * eself;
    const unsigned selfmeta = ((unsigned)f2bf(__expf(eself)) << 16) | (unsigned)node;
    const int items = c + 1;

    f32x2 acc0 = {0.f, 0.f}, acc1 = {0.f, 0.f}, acc2 = {0.f, 0.f}, acc3 = {0.f, 0.f};
    float dsum = 0.f;   // per-half partial

    int it = 0;
    for (; it + 16 <= c; it += 16) {          // 8 pair-rows in flight, all regs named
        const int bi = __builtin_amdgcn_readfirstlane(base + it);
        const uint4 pA = *(const uint4*)&sedge[bi];
        const uint4 pB = *(const uint4*)&sedge[bi + 4];
        const uint4 pC = *(const uint4*)&sedge[bi + 8];
        const uint4 pD = *(const uint4*)&sedge[bi + 12];
        const unsigned m0 = hf ? pA.y : pA.x;
        const unsigned m1 = hf ? pA.w : pA.z;
        const unsigned m2 = hf ? pB.y : pB.x;
        const unsigned m3 = hf ? pB.w : pB.z;
        const unsigned m4 = hf ? pC.y : pC.x;
        const unsigned m5 = hf ? pC.w : pC.z;
        const unsigned m6 = hf ? pD.y : pD.x;
        const unsigned m7 = hf ? pD.w : pD.z;
        const uint4 r0 = hrow[(size_t)(m0 & 0xffffu) * 32 + q];
        const uint4 r1 = hrow[(size_t)(m1 & 0xffffu) * 32 + q];
        const uint4 r2 = hrow[(size_t)(m2 & 0xffffu) * 32 + q];
        const uint4 r3 = hrow[(size_t)(m3 & 0xffffu) * 32 + q];
        const uint4 r4 = hrow[(size_t)(m4 & 0xffffu) * 32 + q];
        const uint4 r5 = hrow[(size_t)(m5 & 0xffffu) * 32 + q];
        const uint4 r6 = hrow[(size_t)(m6 & 0xffffu) * 32 + q];
        const uint4 r7 = hrow[(size_t)(m7 & 0xffffu) * 32 + q];
        float w;
        w = __uint_as_float(m0 & 0xffff0000u); dsum += w;
        fma2(acc0, r0.x, w); fma2(acc1, r0.y, w); fma2(acc2, r0.z, w); fma2(acc3, r0.w, w);
        w = __uint_as_float(m1 & 0xffff0000u); dsum += w;
        fma2(acc0, r1.x, w); fma2(acc1, r1.y, w); fma2(acc2, r1.z, w); fma2(acc3, r1.w, w);
        w = __uint_as_float(m2 & 0xffff0000u); dsum += w;
        fma2(acc0, r2.x, w); fma2(acc1, r2.y, w); fma2(acc2, r2.z, w); fma2(acc3, r2.w, w);
        w = __uint_as_float(m3 & 0xffff0000u); dsum += w;
        fma2(acc0, r3.x, w); fma2(acc1, r3.y, w); fma2(acc2, r3.z, w); fma2(acc3, r3.w, w);
        w = __uint_as_float(m4 & 0xffff0000u); dsum += w;
        fma2(acc0, r4.x, w); fma2(acc1, r4.y, w); fma2(acc2, r4.z, w); fma2(acc3, r4.w, w);
        w = __uint_as_float(m5 & 0xffff0000u); dsum += w;
        fma2(acc0, r5.x, w); fma2(acc1, r5.y, w); fma2(acc2, r5.z, w); fma2(acc3, r5.w, w);
        w = __uint_as_float(m6 & 0xffff0000u); dsum += w;
        fma2(acc0, r6.x, w); fma2(acc1, r6.y, w); fma2(acc2, r6.z, w); fma2(acc3, r6.w, w);
        w = __uint_as_float(m7 & 0xffff0000u); dsum += w;
        fma2(acc0, r7.x, w); fma2(acc1, r7.y, w); fma2(acc2, r7.z, w); fma2(acc3, r7.w, w);
    }
    for (; it < items; it += 2) {             // tail (includes self at index c)
        const int bi = __builtin_amdgcn_readfirstlane(base + it);
        const unsigned t0 = (it     < c) ? sedge[bi]     : ((it     == c) ? selfmeta : 0u);
        const unsigned t1 = (it + 1 < c) ? sedge[bi + 1] : ((it + 1 == c) ? selfmeta : 0u);
        const unsigned m = hf ? t1 : t0;
        const uint4 r = hrow[(size_t)(m & 0xffffu) * 32 + q];
        const float w = __uint_as_float(m & 0xffff0000u);
        dsum += w;
        fma2(acc0, r.x, w); fma2(acc1, r.y, w);
        fma2(acc2, r.z, w); fma2(acc3, r.w, w);
    }

    // combine halves (edge subsets were split across lane halves)
    dsum += __shfl_xor(dsum, 32);
    acc0.x += __shfl_xor(acc0.x, 32); acc0.y += __shfl_xor(acc0.y, 32);
    acc1.x += __shfl_xor(acc1.x, 32); acc1.y += __shfl_xor(acc1.y, 32);
    acc2.x += __shfl_xor(acc2.x, 32); acc2.y += __shfl_xor(acc2.y, 32);
    acc3.x += __shfl_xor(acc3.x, 32); acc3.y += __shfl_xor(acc3.y, 32);

    const float inv = 1.f / dsum;
    const f32x2 A = hf ? acc2 : acc0;         // this lane's 4 output channels
    const f32x2 B = hf ? acc3 : acc1;
    const int ch = q * 8 + hf * 4;
    const float4 b4 = *(const float4*)&bias[ch];
    float4 o;
    o.x = fmaf(A.x, inv, b4.x);
    o.y = fmaf(A.y, inv, b4.y);
    o.z = fmaf(B.x, inv, b4.z);
    o.w = fmaf(B.y, inv, b4.w);
    *(float4*)&out[(size_t)node * NODES_C + ch] = o;
}

extern "C" void kernel_launch(void* const* d_in, const int* in_sizes, int n_in,
                              void* d_out, int out_size, void* d_ws, size_t ws_size,
                              hipStream_t stream) {
    const float* x       = (const float*)d_in[0];
    const int*   edge    = (const int*)d_in[1];
    const float* W       = (const float*)d_in[2];
    const float* att_src = (const float*)d_in[3];
    const float* att_dst = (const float*)d_in[4];
    const float* bias    = (const float*)d_in[5];
    float* out = (float*)d_out;

    const int n = in_sizes[0] / NODES_C;   // 50000
    const int E = in_sizes[1] / 2;         // 1600000
    const int Mpad = (n + 127) & ~127;     // 50048
    const int* src = edge;
    const int* dst = edge + E;

    // workspace carve (256B-aligned blocks)
    char* p = (char*)d_ws;
    auto carve = [&p](size_t bytes) { char* r = p; p += (bytes + 255) & ~(size_t)255; return r; };
    unsigned short* wt = (unsigned short*)carve((size_t)NODES_C * NODES_C * 2);
    unsigned short* hb = (unsigned short*)carve((size_t)n * NODES_C * 2);     // 25.6 MB
    float* a_s = (float*)carve((size_t)n * 4 * 3);   // a_s | a_d | cnt (one zero pass)
    float* a_d = a_s + n;
    int*   cnt = (int*)(a_d + n);
    unsigned* sedge = (unsigned*)carve((size_t)n * CAP * 4);                  // 25.6 MB

    const int nZero4 = (n * 3) / 4;                      // 37500 uint4
    const int nbZero = (nZero4 + 1023) / 1024;           // 37
    const int nbCvtw = (NODES_C * NODES_C) / 1024;       // 64

    k_init<<<nbZero + nbCvtw, 256, 0, stream>>>(W, wt, (uint4*)a_s, nZero4, nbZero);
    k_stageB<<<(Mpad / 128) * 2, 256, 0, stream>>>(
        x, wt, att_src, att_dst, hb, a_s, a_d, n);

    const int E4 = E / 4;                                // 400000 (E % 4 == 0)
    const int bps = 192;                                 // blocks per slice
    const int nsNode = (n + NSLICE - 1) / NSLICE;        // 6250
    k_permute<<<bps * NSLICE, 256, 0, stream>>>(src, dst, a_s, a_d, cnt, sedge,
                                                E4, bps, nsNode, n);
    k_gather<<<(n + 3) / 4, 256, 0, stream>>>(cnt, sedge, hb, a_s, a_d, bias, out, n);
}